// Round 4
// baseline (690.945 us; speedup 1.0000x reference)
//
#include <hip/hip_runtime.h>
#include <cstdint>

#define D_DIM 1024
#define V_DIM 32000
#define S_DIM 512
#define M_TOK 77
#define ROWS 2464
#define ROWS_PAD 2560

// ---- gemm2 (256^2, BK=64, ping-pong, m201 4-phase/K-tile) geometry ----
#define G2_BM 256
#define G2_BN 256
#define G2_BK 64
#define G2_MT (ROWS_PAD / G2_BM)  // 10
#define G2_NT (V_DIM / G2_BN)     // 125
#define G2_NWG (G2_MT * G2_NT)    // 1250
#define G2_KT (D_DIM / G2_BK)     // 16 K-tiles

typedef __attribute__((ext_vector_type(8))) short bf16x8;
typedef __attribute__((ext_vector_type(4))) float f32x4;
typedef __attribute__((ext_vector_type(4))) uint16_t u16x4;

__device__ __forceinline__ uint16_t f2bf(float f) {
    union { float f; uint32_t u; } w; w.f = f;
    uint32_t r = (w.u + 0x7FFFu + ((w.u >> 16) & 1u)) >> 16;
    return (uint16_t)r;
}

__device__ __forceinline__ void async_copy16(const uint16_t* g, uint16_t* l) {
    __builtin_amdgcn_global_load_lds((const __attribute__((address_space(1))) void*)g,
                                     (__attribute__((address_space(3))) void*)l,
                                     16, 0, 0);
}

// ------- transpose+cast: in fp32 [R][C] -> out bf16 [C][R], 64x64 tiles ----
__global__ __launch_bounds__(256) void transpose_f32_bf16(const float* __restrict__ in,
                                                          uint16_t* __restrict__ out,
                                                          int R, int C) {
    __shared__ uint16_t tile[64][65];
    const int c0 = blockIdx.x * 64, r0 = blockIdx.y * 64;
    const int t  = threadIdx.x;
    const int lr = t >> 4;          // 0..15
    const int lc = (t & 15) * 4;    // 0..60
#pragma unroll
    for (int p = 0; p < 4; ++p) {
        const float* src = in + (size_t)(r0 + p * 16 + lr) * C + c0 + lc;
        f32x4 v = *(const f32x4*)src;
        tile[p * 16 + lr][lc + 0] = f2bf(v.x);
        tile[p * 16 + lr][lc + 1] = f2bf(v.y);
        tile[p * 16 + lr][lc + 2] = f2bf(v.z);
        tile[p * 16 + lr][lc + 3] = f2bf(v.w);
    }
    __syncthreads();
#pragma unroll
    for (int p = 0; p < 4; ++p) {
        const int oc = p * 16 + lr;  // col index within tile -> out row c0+oc
        u16x4 v;
        v.x = tile[lc + 0][oc];
        v.y = tile[lc + 1][oc];
        v.z = tile[lc + 2][oc];
        v.w = tile[lc + 3][oc];
        *(u16x4*)(out + (size_t)(c0 + oc) * R + r0 + lc) = v;
    }
}

// ------- gather+cast masked rows: Ag[r][:] = bf16(X[b, pos[r], :]) --------
__global__ __launch_bounds__(256) void gather_rows(const float* __restrict__ X,
                                                   const int* __restrict__ pos,
                                                   uint16_t* __restrict__ Ag) {
    const int r = blockIdx.x;
    const int t = threadIdx.x;
    size_t src = 0;
    if (r < ROWS) {
        const int b = r / M_TOK;
        const int p = pos[r];      // pos is [B][M] contiguous; flat idx == r
        src = ((size_t)b * S_DIM + p) * D_DIM;
    }
    f32x4 v = *(const f32x4*)(X + src + t * 4);
    u16x4 o;
    o.x = f2bf(v.x); o.y = f2bf(v.y); o.z = f2bf(v.z); o.w = f2bf(v.w);
    *(u16x4*)(Ag + (size_t)r * D_DIM + t * 4) = o;
}

// ------- m97-style GEMM (kept for the small GEMM1): C = A * B^T + bias ----
template <int EPI>
__global__ __launch_bounds__(256, 2) void gemm_bt(const uint16_t* __restrict__ A,
                                                  const uint16_t* __restrict__ B,
                                                  const float* __restrict__ bias,
                                                  float* __restrict__ C,
                                                  int K, int N, int MValid) {
    __shared__ uint16_t As[128 * 64];
    __shared__ uint16_t Bs[128 * 64];
    const int tid  = threadIdx.x;
    const int lane = tid & 63;
    const int wave = tid >> 6;
    const int wr   = (wave >> 1) * 64;
    const int wc   = (wave & 1) * 64;
    const int tM   = blockIdx.y * 128;
    const int tN   = blockIdx.x * 128;
    const int l15  = lane & 15;
    const int l4   = lane >> 4;

    const f32x4 zero = {0.f, 0.f, 0.f, 0.f};
    f32x4 acc[4][4];
#pragma unroll
    for (int i = 0; i < 4; ++i)
#pragma unroll
        for (int j = 0; j < 4; ++j) acc[i][j] = zero;

    const uint16_t* Agp = A + (size_t)(tM + (tid >> 3)) * K + (tid & 7) * 8;
    const uint16_t* Bgp = B + (size_t)(tN + (tid >> 3)) * K + (tid & 7) * 8;
    uint16_t* Asl = &As[tid * 8];
    uint16_t* Bsl = &Bs[tid * 8];
    const size_t rstep = (size_t)32 * K;

    for (int k0 = 0; k0 < K; k0 += 64) {
#pragma unroll
        for (int i = 0; i < 4; ++i)
            async_copy16(Agp + i * rstep + k0, Asl + i * 2048);
#pragma unroll
        for (int i = 0; i < 4; ++i)
            async_copy16(Bgp + i * rstep + k0, Bsl + i * 2048);
        __syncthreads();
#pragma unroll
        for (int kk = 0; kk < 2; ++kk) {
            bf16x8 af[4], bfr[4];
#pragma unroll
            for (int i = 0; i < 4; ++i)
                af[i] = *(const bf16x8*)&As[(wr + i * 16 + l15) * 64 + kk * 32 + l4 * 8];
#pragma unroll
            for (int j = 0; j < 4; ++j)
                bfr[j] = *(const bf16x8*)&Bs[(wc + j * 16 + l15) * 64 + kk * 32 + l4 * 8];
#pragma unroll
            for (int i = 0; i < 4; ++i)
#pragma unroll
                for (int j = 0; j < 4; ++j)
                    acc[i][j] = __builtin_amdgcn_mfma_f32_16x16x32_bf16(af[i], bfr[j],
                                                                        acc[i][j], 0, 0, 0);
        }
        __syncthreads();
    }

#pragma unroll
    for (int j = 0; j < 4; ++j) {
        const int col = tN + wc + j * 16 + l15;
        const float bv = bias[col];
#pragma unroll
        for (int i = 0; i < 4; ++i) {
            const int row0 = tM + wr + i * 16 + l4 * 4;
#pragma unroll
            for (int r = 0; r < 4; ++r) {
                const int row = row0 + r;
                float v = acc[i][j][r] + bv;
                if (EPI == 0) {
                    v = v > 0.f ? v : 0.f;
                    C[(size_t)row * N + col] = v;
                } else {
                    if (row < MValid)
                        C[(size_t)row * N + col] = v;
                }
            }
        }
    }
}

// ------- GEMM2: 256x256, BK=64, ping-pong LDS, m201 4-phase schedule ------
// C[2560,32000] = A[2560,1024] * B^T[32000,1024] + bias, fp32 out, row mask.
// LDS 128 KiB = 2 x { A[256][64] | B[256][64] } bf16, XOR-swizzled (R1 swizzle,
// measured 0 conflicts).  Phase = one C-quadrant x K=64 (16 MFMA), with
// {reads ; 2 stages ; barrier ; lgkmcnt(0) ; setprio ; MFMA ; setprio ; barrier}.
// Disjoint acc registers per phase -> next phase's ds_reads issue while the
// previous MFMA cluster drains the matrix pipe.  vmcnt(2) ONCE per K-tile at
// P3 (between stage and pre-MFMA barrier); never drains in steady state.
#define G2B(T) (((T) & 1) * 32768)
#define BAR    __builtin_amdgcn_s_barrier()
#define LGKM0  asm volatile("s_waitcnt lgkmcnt(0)" ::: "memory")

#define RD_FA(T, H)                                                                         \
    _Pragma("unroll") for (int i = 0; i < 4; ++i) {                                         \
        fa[i * 2 + 0] = *(const bf16x8*)&lds[G2B(T) + (R0 + (H) * 64 + i * 16 + l15) * 64 + colk0]; \
        fa[i * 2 + 1] = *(const bf16x8*)&lds[G2B(T) + (R0 + (H) * 64 + i * 16 + l15) * 64 + colk1]; \
    }

#define RD_FB(T, FB, J0)                                                                    \
    _Pragma("unroll") for (int j = 0; j < 2; ++j) {                                         \
        FB[j * 2 + 0] = *(const bf16x8*)&lds[G2B(T) + 16384 + (C0 + ((J0) + j) * 16 + l15) * 64 + colk0]; \
        FB[j * 2 + 1] = *(const bf16x8*)&lds[G2B(T) + 16384 + (C0 + ((J0) + j) * 16 + l15) * 64 + colk1]; \
    }

#define STG(T, G)                                                                 \
    do {                                                                          \
        const int sb_ = G2B(T);                                                   \
        async_copy16(Ags + (size_t)(G) * 64 * D_DIM + (T) * G2_BK, AsD + sb_ + (G) * 4096); \
        async_copy16(Bgs + (size_t)(G) * 64 * D_DIM + (T) * G2_BK, BsD + sb_ + (G) * 4096); \
    } while (0)

#define MM(H, JP, FB)                                                                       \
    __builtin_amdgcn_s_setprio(1);                                                          \
    _Pragma("unroll") for (int i = 0; i < 4; ++i)                                           \
    _Pragma("unroll") for (int j = 0; j < 2; ++j)                                           \
    _Pragma("unroll") for (int kk = 0; kk < 2; ++kk)                                        \
        acc[(H) * 4 + i][(JP) * 2 + j] =                                                    \
            __builtin_amdgcn_mfma_f32_16x16x32_bf16(fa[i * 2 + kk], FB[j * 2 + kk],         \
                                                    acc[(H) * 4 + i][(JP) * 2 + j], 0, 0, 0); \
    __builtin_amdgcn_s_setprio(0);

// One K-tile: S1 = stage tile T+1 (groups 1..3), S2 = stage tile T+2 group 0,
// VM = vmcnt immediate at P3 (2 steady, 0 at tail).
#define KTILE(T, S1, S2, VM)                                  \
    do {                                                      \
        /* P0: quad(lo, j01) */                               \
        RD_FA(T, 0); RD_FB(T, fbA, 0);                        \
        if (S1) STG((T) + 1, 1);                              \
        BAR; LGKM0; MM(0, 0, fbA); BAR;                       \
        /* P1: quad(lo, j23) */                               \
        RD_FB(T, fbB, 2);                                     \
        if (S1) STG((T) + 1, 2);                              \
        BAR; LGKM0; MM(0, 1, fbB); BAR;                       \
        /* P2: quad(hi, j01) */                               \
        RD_FA(T, 1);                                          \
        if (S1) STG((T) + 1, 3);                              \
        BAR; LGKM0; MM(1, 0, fbA); BAR;                       \
        /* P3: quad(hi, j23); seam vmcnt between stage and pre-MFMA barrier */ \
        if (S2) STG((T) + 2, 0);                              \
        asm volatile("s_waitcnt vmcnt(" #VM ")" ::: "memory"); \
        BAR; MM(1, 1, fbB); BAR;                              \
    } while (0)

__global__ __launch_bounds__(512, 2) void gemm2_256(const uint16_t* __restrict__ A,
                                                    const uint16_t* __restrict__ B,
                                                    const float* __restrict__ bias,
                                                    float* __restrict__ C,
                                                    int MValid) {
    __shared__ uint16_t lds[65536];   // 128 KiB = 2 x 64 KiB ping-pong
    const int tid  = threadIdx.x;
    const int lane = tid & 63;
    const int wave = tid >> 6;        // 0..7
    const int l15  = lane & 15;
    const int l4   = lane >> 4;       // 0..3
    const int R0   = (wave >> 2) * 128;  // wave row base (2 waves in M)
    const int C0   = (wave & 3) * 64;    // wave col base (4 waves in N)

    // T1: bijective XCD-chunked swizzle (m204); tM-fast => consecutive logical
    // blocks share the 512KB B-panel within one XCD's L2.
    const int bid = blockIdx.x;
    const int q = G2_NWG >> 3, r = G2_NWG & 7;
    const int xcd = bid & 7, lin = bid >> 3;
    const int wg = (xcd < r ? xcd * (q + 1) : r * (q + 1) + (xcd - r) * q) + lin;
    const int tM = (wg % G2_MT) * G2_BM;
    const int tN = (wg / G2_MT) * G2_BN;

    // Staging: linear LDS dest + inverse-swizzled GLOBAL source column.
    // LDS element (row, ce) lives at row*64 + (ce ^ ((row&7)<<3))  [R1 swizzle,
    // measured 0 bank conflicts].
    const int srow  = tid >> 3;                                   // 0..63
    const int swcol = (((tid & 7) ^ (srow & 7)) << 3);            // element col
    const uint16_t* Ags = A + (size_t)(tM + srow) * D_DIM + swcol;
    const uint16_t* Bgs = B + (size_t)(tN + srow) * D_DIM + swcol;
    uint16_t* AsD = &lds[tid * 8];
    uint16_t* BsD = &lds[16384 + tid * 8];

    // swizzled read columns (elements) for kk=0 / kk=1
    const int colk0 = (l4 * 8) ^ ((l15 & 7) << 3);
    const int colk1 = colk0 ^ 32;

    const f32x4 zero = {0.f, 0.f, 0.f, 0.f};
    f32x4 acc[8][4];
#pragma unroll
    for (int i = 0; i < 8; ++i)
#pragma unroll
        for (int j = 0; j < 4; ++j) acc[i][j] = zero;

    bf16x8 fa[8], fbA[4], fbB[4];

    // ---- prologue: stage tile 0 fully + tile 1 group 0; establish seam ----
#pragma unroll
    for (int g = 0; g < 4; ++g) STG(0, g);
    STG(1, 0);
    asm volatile("s_waitcnt vmcnt(2)" ::: "memory");   // tile 0 landed, t1g0 in flight
    BAR;

    // ---- main loop: steady state, vmcnt(2) once per K-tile, never drains ----
#pragma unroll 2
    for (int T = 0; T < G2_KT - 2; ++T)    // T = 0..13
        KTILE(T, 1, 1, 2);
    // ---- tail: T = 14 (stage tile 15 g1..3, drain), T = 15 (no stages) ----
    KTILE(14, 1, 0, 0);
    KTILE(15, 0, 0, 0);

    // ---- epilogue: D mapping (16x16x32): row = l4*4 + rr, col = l15 ----
#pragma unroll
    for (int j = 0; j < 4; ++j) {
        const int col = tN + C0 + j * 16 + l15;
        const float bv = bias[col];
#pragma unroll
        for (int i = 0; i < 8; ++i) {
            const int row0 = tM + R0 + i * 16 + l4 * 4;   // i<4 rows 0..63, i>=4 rows 64..127
#pragma unroll
            for (int rr = 0; rr < 4; ++rr) {
                const int row = row0 + rr;
                if (row < MValid)
                    C[(size_t)row * V_DIM + col] = acc[i][j][rr] + bv;
            }
        }
    }
}

// ------- row LayerNorm: H fp32 [ROWS_PAD][1024] -> Hn bf16 ----------------
__global__ __launch_bounds__(256) void layernorm_rows(const float* __restrict__ H,
                                                      const float* __restrict__ gamma,
                                                      const float* __restrict__ beta,
                                                      uint16_t* __restrict__ Hn) {
    const int row = blockIdx.x;
    const int t   = threadIdx.x;
    const float* h = H + (size_t)row * D_DIM;
    f32x4 v = *(const f32x4*)(h + t * 4);
    float s  = v.x + v.y + v.z + v.w;
    float sq = v.x * v.x + v.y * v.y + v.z * v.z + v.w * v.w;
#pragma unroll
    for (int o = 32; o > 0; o >>= 1) {
        s  += __shfl_down(s, o, 64);
        sq += __shfl_down(sq, o, 64);
    }
    __shared__ float ss[4], sqs[4];
    if ((t & 63) == 0) { ss[t >> 6] = s; sqs[t >> 6] = sq; }
    __syncthreads();
    const float S    = ss[0] + ss[1] + ss[2] + ss[3];
    const float SQ   = sqs[0] + sqs[1] + sqs[2] + sqs[3];
    const float mean = S * (1.f / D_DIM);
    const float var  = SQ * (1.f / D_DIM) - mean * mean;
    const float rstd = rsqrtf(var + 1e-5f);
    const int c = t * 4;
    f32x4 g = *(const f32x4*)(gamma + c);
    f32x4 bt = *(const f32x4*)(beta + c);
    u16x4 o;
    o.x = f2bf((v.x - mean) * rstd * g.x + bt.x);
    o.y = f2bf((v.y - mean) * rstd * g.y + bt.y);
    o.z = f2bf((v.z - mean) * rstd * g.z + bt.z);
    o.w = f2bf((v.w - mean) * rstd * g.w + bt.w);
    *(u16x4*)(Hn + (size_t)row * D_DIM + c) = o;
}

extern "C" void kernel_launch(void* const* d_in, const int* in_sizes, int n_in,
                              void* d_out, int out_size, void* d_ws, size_t ws_size,
                              hipStream_t stream) {
    const float* X     = (const float*)d_in[0];
    const int*   mp    = (const int*)d_in[1];
    const float* W1    = (const float*)d_in[2];
    const float* b1    = (const float*)d_in[3];
    const float* gamma = (const float*)d_in[4];
    const float* beta  = (const float*)d_in[5];
    const float* W2    = (const float*)d_in[6];
    const float* b2    = (const float*)d_in[7];

    char* ws = (char*)d_ws;
    uint16_t* W2T = (uint16_t*)(ws);                                           // 65,536,000 B
    uint16_t* W1T = (uint16_t*)(ws + 65536000);                                //  2,097,152 B
    uint16_t* Ag  = (uint16_t*)(ws + 65536000 + 2097152);                      //  5,242,880 B
    uint16_t* Hn  = (uint16_t*)(ws + 65536000 + 2097152 + 5242880);            //  5,242,880 B
    float*    H   = (float*)   (ws + 65536000 + 2097152 + 5242880 + 5242880);  // 10,485,760 B

    // W2 fp32 [1024][32000] -> W2T bf16 [32000][1024]; W1 likewise
    transpose_f32_bf16<<<dim3(V_DIM / 64, D_DIM / 64), 256, 0, stream>>>(W2, W2T, D_DIM, V_DIM);
    transpose_f32_bf16<<<dim3(D_DIM / 64, D_DIM / 64), 256, 0, stream>>>(W1, W1T, D_DIM, D_DIM);
    // gather masked rows (padded to 2560 with row 0 data), cast to bf16
    gather_rows<<<ROWS_PAD, 256, 0, stream>>>(X, mp, Ag);
    // H = relu(Ag @ W1 + b1)   [2560][1024] fp32
    gemm_bt<0><<<dim3(D_DIM / 128, ROWS_PAD / 128), 256, 0, stream>>>(Ag, W1T, b1, H,
                                                                      D_DIM, D_DIM, ROWS_PAD);
    // Hn = LN(H) * gamma + beta  -> bf16
    layernorm_rows<<<ROWS_PAD, 256, 0, stream>>>(H, gamma, beta, Hn);
    // out = Hn @ W2 + b2  [2464][32000] fp32  (m201 4-phase kernel)
    gemm2_256<<<dim3(G2_NWG), 512, 0, stream>>>(Hn, W2T, b2, (float*)d_out, ROWS);
}